// Round 1
// baseline (62.997 us; speedup 1.0000x reference)
//
#include <hip/hip_runtime.h>

// MosaicSDF: N=1024 points, G=512 grids, K=7 (343 nodes/grid).
// Layout: one block per grid. LDS-staged vals+coords, block-level
// compaction of active pairs (||rel|| < 1), global f32 atomics for the
// cross-grid reduction, tiny finalize kernel.

#define NPTS   1024
#define NGRIDS 512
#define KCUBE  343
#define TPB    512

__global__ __launch_bounds__(TPB) void msdf_pairs(
    const float* __restrict__ points,    // (N,3)
    const float* __restrict__ centers,   // (G,3)
    const float* __restrict__ scales,    // (G,)
    const float* __restrict__ vals,      // (G,343)
    float* __restrict__ num,             // (N,)  accumulators (pre-zeroed)
    float* __restrict__ den)             // (N,)
{
    __shared__ float4 s_coords[KCUBE];   // node coords (x,y,z,unused)
    __shared__ float  s_vals[KCUBE];
    __shared__ int    s_actN[NPTS];
    __shared__ float  s_relx[NPTS], s_rely[NPTS], s_relz[NPTS], s_gwr[NPTS];
    __shared__ int    s_cnt;

    const int g = blockIdx.x;
    const int t = threadIdx.x;
    if (t == 0) s_cnt = 0;

    // Stage per-grid SDF values and the 7x7x7 node coordinates.
    if (t < KCUBE) {
        s_vals[t] = vals[g * KCUBE + t];
        int i = t / 49;
        int r = t - i * 49;
        int j = r / 7;
        int l = r - j * 7;
        const float inv6 = 1.0f / 6.0f;
        s_coords[t] = make_float4(i * inv6, j * inv6, l * inv6, 0.0f);
    }

    const float cx   = centers[g * 3 + 0];
    const float cy   = centers[g * 3 + 1];
    const float cz   = centers[g * 3 + 2];
    const float invs = 1.0f / scales[g];
    __syncthreads();

    // Phase A: per-point blend weight; compact active pairs into LDS.
    for (int n = t; n < NPTS; n += TPB) {
        float px = points[n * 3 + 0];
        float py = points[n * 3 + 1];
        float pz = points[n * 3 + 2];
        float rx = (px - cx) * invs;
        float ry = (py - cy) * invs;
        float rz = (pz - cz) * invs;
        float r2 = rx * rx + ry * ry + rz * rz;
        float gwr = 1.0f - sqrtf(r2);     // relu(1 - ||rel||)
        if (gwr > 0.0f) {
            int slot = atomicAdd(&s_cnt, 1);
            s_actN[slot] = n;
            s_relx[slot] = rx;
            s_rely[slot] = ry;
            s_relz[slot] = rz;
            s_gwr[slot]  = gwr;
            atomicAdd(&den[n], gwr);
        }
    }
    __syncthreads();

    // Phase B: 343-node trilinear-ish weighted interpolation, actives only.
    const int cnt = s_cnt;
    for (int a = t; a < cnt; a += TPB) {
        const float rx  = s_relx[a];
        const float ry  = s_rely[a];
        const float rz  = s_relz[a];
        const float gwr = s_gwr[a];
        const int   n   = s_actN[a];
        float wsum = 0.0f, vsum = 0.0f;
        #pragma unroll 7
        for (int c = 0; c < KCUBE; ++c) {
            float4 cc = s_coords[c];       // LDS broadcast (uniform addr)
            float dx = rx - cc.x;
            float dy = ry - cc.y;
            float dz = rz - cc.z;
            float d2 = dx * dx + dy * dy + dz * dz;
            float w  = (d2 <= 1.0f) ? sqrtf(d2) : 0.0f;   // dist<=1 ? dist : 0
            wsum += w;
            vsum  = fmaf(w, s_vals[c], vsum);
        }
        float interp = (wsum > 0.0f) ? (vsum / wsum) : 0.0f;
        atomicAdd(&num[n], interp * gwr);
    }
}

__global__ __launch_bounds__(256) void msdf_final(
    const float* __restrict__ num,
    const float* __restrict__ den,
    float* __restrict__ out)
{
    int n = blockIdx.x * blockDim.x + threadIdx.x;
    if (n < NPTS) {
        float d = den[n];
        out[n] = (d > 0.0f) ? (num[n] / d) : 0.0f;
    }
}

extern "C" void kernel_launch(void* const* d_in, const int* in_sizes, int n_in,
                              void* d_out, int out_size, void* d_ws, size_t ws_size,
                              hipStream_t stream) {
    const float* points  = (const float*)d_in[0];   // (1024,3)
    const float* centers = (const float*)d_in[1];   // (512,3)
    const float* scales  = (const float*)d_in[2];   // (512,)
    const float* vals    = (const float*)d_in[3];   // (512,7,7,7)
    float* out = (float*)d_out;                     // (1024,)

    float* num = (float*)d_ws;                      // 1024 floats
    float* den = num + NPTS;                        // 1024 floats

    hipMemsetAsync(d_ws, 0, 2 * NPTS * sizeof(float), stream);
    msdf_pairs<<<NGRIDS, TPB, 0, stream>>>(points, centers, scales, vals, num, den);
    msdf_final<<<(NPTS + 255) / 256, 256, 0, stream>>>(num, den, out);
}

// Round 2
// 40.851 us; speedup vs baseline: 1.5421x; 1.5421x over previous
//
#include <hip/hip_runtime.h>

// MosaicSDF: N=1024 points, G=512 grids, K=7 (343 nodes/grid).
// One block per point, 8 waves x 64 lanes; lane <-> grid for the activity
// check, ballot-compaction, then all 64 lanes cooperate on each active
// pair's 343-node loop (<=6 nodes/lane + shuffle reduce). No atomics,
// no workspace, single kernel.

#define NPTS   1024
#define NGRIDS 512
#define KCUBE  343
#define TPB    512
#define WAVES  (TPB / 64)

__global__ __launch_bounds__(TPB) void msdf_fused(
    const float* __restrict__ points,    // (N,3)
    const float* __restrict__ centers,   // (G,3)
    const float* __restrict__ scales,    // (G,)
    const float* __restrict__ vals,      // (G,343)
    float* __restrict__ out)             // (N,)
{
    __shared__ float s_num[WAVES];
    __shared__ float s_den[WAVES];

    const int n    = blockIdx.x;
    const int t    = threadIdx.x;
    const int w    = t >> 6;
    const int lane = t & 63;
    const int g    = w * 64 + lane;      // this lane's grid

    // Point coords (uniform across block -> broadcast loads).
    const float px = points[n * 3 + 0];
    const float py = points[n * 3 + 1];
    const float pz = points[n * 3 + 2];

    // Per-lane grid data (6 KB + 2 KB tables, L1/L2 resident).
    const float cx   = centers[g * 3 + 0];
    const float cy   = centers[g * 3 + 1];
    const float cz   = centers[g * 3 + 2];
    const float invs = 1.0f / scales[g];

    const float rx = (px - cx) * invs;
    const float ry = (py - cy) * invs;
    const float rz = (pz - cz) * invs;
    const float r2 = rx * rx + ry * ry + rz * rz;
    const float gwr  = 1.0f - sqrtf(r2);            // relu(1-||rel||) pre-clamp
    const float gpos = (gwr > 0.0f) ? gwr : 0.0f;

    // Wave-reduce the per-grid blend-weight denominator partial.
    float dsum = gpos;
    #pragma unroll
    for (int off = 32; off >= 1; off >>= 1) dsum += __shfl_xor(dsum, off);

    // Compact active grids of this wave; cooperate on each.
    unsigned long long mask = __ballot(gwr > 0.0f);
    float numAcc = 0.0f;
    const float inv6 = 1.0f / 6.0f;

    while (mask) {
        const int b = (int)__builtin_ctzll(mask);   // next active lane/grid
        mask &= mask - 1;
        const float brx = __shfl(rx, b);
        const float bry = __shfl(ry, b);
        const float brz = __shfl(rz, b);
        const float bgw = __shfl(gwr, b);
        const int   bg  = w * 64 + b;
        const float* __restrict__ gv = vals + bg * KCUBE;

        float wsum = 0.0f, vsum = 0.0f;
        for (int c = lane; c < KCUBE; c += 64) {    // <=6 nodes per lane
            const int i = c / 49;
            const int r = c - i * 49;
            const int j = r / 7;
            const int l = r - j * 7;
            const float dx = brx - (float)i * inv6;
            const float dy = bry - (float)j * inv6;
            const float dz = brz - (float)l * inv6;
            const float d2 = dx * dx + dy * dy + dz * dz;
            const float wt = (d2 <= 1.0f) ? sqrtf(d2) : 0.0f;  // dist<=1?dist:0
            wsum += wt;
            vsum  = fmaf(wt, gv[c], vsum);          // coalesced, L2-hit
        }
        #pragma unroll
        for (int off = 32; off >= 1; off >>= 1) {
            wsum += __shfl_xor(wsum, off);
            vsum += __shfl_xor(vsum, off);
        }
        const float interp = (wsum > 0.0f) ? (vsum / wsum) : 0.0f;
        numAcc += interp * bgw;                     // redundant on all lanes
    }

    if (lane == 0) { s_num[w] = numAcc; s_den[w] = dsum; }
    __syncthreads();
    if (t == 0) {
        float ns = 0.0f, ds = 0.0f;
        #pragma unroll
        for (int i = 0; i < WAVES; ++i) { ns += s_num[i]; ds += s_den[i]; }
        out[n] = (ds > 0.0f) ? (ns / ds) : 0.0f;
    }
}

extern "C" void kernel_launch(void* const* d_in, const int* in_sizes, int n_in,
                              void* d_out, int out_size, void* d_ws, size_t ws_size,
                              hipStream_t stream) {
    const float* points  = (const float*)d_in[0];   // (1024,3)
    const float* centers = (const float*)d_in[1];   // (512,3)
    const float* scales  = (const float*)d_in[2];   // (512,)
    const float* vals    = (const float*)d_in[3];   // (512,7,7,7)
    float* out = (float*)d_out;                     // (1024,)

    msdf_fused<<<NPTS, TPB, 0, stream>>>(points, centers, scales, vals, out);
}

// Round 3
// 32.970 us; speedup vs baseline: 1.9108x; 1.2391x over previous
//
#include <hip/hip_runtime.h>

// MosaicSDF: N=1024 points, G=512 grids, K=7 (343 nodes/grid).
// One block per point, 8 waves x 64 lanes. Lane <-> grid activity check,
// then batches of 8 active pairs per wave: 8 groups x 8 lanes, each group
// owns one active pair and its lanes split the 343 nodes (<=43 each).
// Coords from an LDS float4 table (broadcast, conflict-free). Group
// reduce = 3-step shfl_xor. No atomics, no workspace.

#define NPTS   1024
#define NGRIDS 512
#define KCUBE  343
#define TPB    512
#define WAVES  (TPB / 64)

__global__ __launch_bounds__(TPB) void msdf_fused(
    const float* __restrict__ points,    // (N,3)
    const float* __restrict__ centers,   // (G,3)
    const float* __restrict__ scales,    // (G,)
    const float* __restrict__ vals,      // (G,343)
    float* __restrict__ out)             // (N,)
{
    __shared__ float4 s_coords[KCUBE];
    __shared__ float  s_num[WAVES];
    __shared__ float  s_den[WAVES];

    const int n    = blockIdx.x;
    const int t    = threadIdx.x;
    const int w    = t >> 6;
    const int lane = t & 63;
    const int grp  = lane >> 3;          // 0..7 : which active pair of the batch
    const int sub  = lane & 7;           // 0..7 : node-slice within the pair
    const int g    = w * 64 + lane;      // this lane's grid for the activity check

    // Stage the 7x7x7 node-coordinate table (one-time, 5.5 KB).
    if (t < KCUBE) {
        const int i = t / 49;
        const int r = t - i * 49;
        const int j = r / 7;
        const int l = r - j * 7;
        const float inv6 = 1.0f / 6.0f;
        s_coords[t] = make_float4(i * inv6, j * inv6, l * inv6, 0.0f);
    }

    // Point (uniform across block) and this lane's grid parameters.
    const float px = points[n * 3 + 0];
    const float py = points[n * 3 + 1];
    const float pz = points[n * 3 + 2];
    const float cx   = centers[g * 3 + 0];
    const float cy   = centers[g * 3 + 1];
    const float cz   = centers[g * 3 + 2];
    const float invs = 1.0f / scales[g];

    const float rx = (px - cx) * invs;
    const float ry = (py - cy) * invs;
    const float rz = (pz - cz) * invs;
    const float gwr = 1.0f - sqrtf(rx * rx + ry * ry + rz * rz);

    // Per-grid blend-weight denominator partial (wave butterfly, once).
    float dsum = (gwr > 0.0f) ? gwr : 0.0f;
    #pragma unroll
    for (int off = 32; off >= 1; off >>= 1) dsum += __shfl_xor(dsum, off);

    unsigned long long mask = __ballot(gwr > 0.0f);

    __syncthreads();                     // coords table ready

    float numAcc = 0.0f;
    while (mask) {
        // Source lane for my group = grp-th set bit of the current mask.
        unsigned long long mm = mask;
        #pragma unroll
        for (int q = 0; q < 7; ++q) if (q < grp) mm &= mm - 1;
        const bool haveWork = (mm != 0ull);
        const int  src      = haveWork ? (int)__builtin_ctzll(mm) : 0;

        // Consume up to 8 active bits (uniform across the wave).
        #pragma unroll
        for (int q = 0; q < 8; ++q) mask &= mask - 1;

        // Broadcast the pair's data from its source lane.
        const float brx = __shfl(rx, src);
        const float bry = __shfl(ry, src);
        const float brz = __shfl(rz, src);
        const float bgw = __shfl(gwr, src);
        const float* __restrict__ gv = vals + (w * 64 + src) * KCUBE;

        float wsum = 0.0f, vsum = 0.0f;
        if (haveWork) {
            #pragma unroll 4
            for (int c = sub; c < KCUBE; c += 8) {   // <=43 nodes per lane
                const float4 cc = s_coords[c];       // broadcast, conflict-free
                const float dx = brx - cc.x;
                const float dy = bry - cc.y;
                const float dz = brz - cc.z;
                const float d2 = fmaf(dx, dx, fmaf(dy, dy, dz * dz));
                const float wt = (d2 <= 1.0f) ? sqrtf(d2) : 0.0f;
                wsum += wt;
                vsum  = fmaf(wt, gv[c], vsum);       // L1/L2-resident
            }
        }
        // Reduce within the 8-lane group (3 steps).
        #pragma unroll
        for (int off = 4; off >= 1; off >>= 1) {
            wsum += __shfl_xor(wsum, off);
            vsum += __shfl_xor(vsum, off);
        }
        const float interp = (wsum > 0.0f) ? (vsum / wsum) : 0.0f;
        if (haveWork && sub == 0) numAcc += interp * bgw;
    }

    // Sum the 8 group contributions (only sub==0 lanes are nonzero).
    #pragma unroll
    for (int off = 32; off >= 1; off >>= 1) numAcc += __shfl_xor(numAcc, off);

    if (lane == 0) { s_num[w] = numAcc; s_den[w] = dsum; }
    __syncthreads();
    if (t == 0) {
        float ns = 0.0f, ds = 0.0f;
        #pragma unroll
        for (int i = 0; i < WAVES; ++i) { ns += s_num[i]; ds += s_den[i]; }
        out[n] = (ds > 0.0f) ? (ns / ds) : 0.0f;
    }
}

extern "C" void kernel_launch(void* const* d_in, const int* in_sizes, int n_in,
                              void* d_out, int out_size, void* d_ws, size_t ws_size,
                              hipStream_t stream) {
    const float* points  = (const float*)d_in[0];   // (1024,3)
    const float* centers = (const float*)d_in[1];   // (512,3)
    const float* scales  = (const float*)d_in[2];   // (512,)
    const float* vals    = (const float*)d_in[3];   // (512,7,7,7)
    float* out = (float*)d_out;                     // (1024,)

    msdf_fused<<<NPTS, TPB, 0, stream>>>(points, centers, scales, vals, out);
}